// Round 1
// baseline (430.201 us; speedup 1.0000x reference)
//
#include <hip/hip_runtime.h>
#include <stdint.h>

#define NROWS 1024
#define NCOLS 16384

typedef unsigned long long u64;
typedef unsigned int u32;

// Persistent device state (re-initialized every kernel_launch call).
__device__ u64 g_rowbest[NROWS];    // key: (sortable_val<<32) | (NCOLS-1-col)
__device__ u64 g_colbest[NCOLS];    // key: (sortable_val<<32) | (NROWS-1-row)
__device__ int g_col_used[NCOLS];
__device__ int g_col_of_row[NROWS];
__device__ int g_remaining[NROWS];
__device__ int g_nrem;

// Monotone float32 -> uint32 mapping (preserves <):
__device__ __forceinline__ u32 fsort(float x) {
    u32 u = __float_as_uint(x);
    return u ^ ((u32)((int)u >> 31) | 0x80000000u);
}

__global__ void k_init() {
    int i = blockIdx.x * blockDim.x + threadIdx.x;
    if (i < NCOLS) { g_colbest[i] = 0ULL; g_col_used[i] = 0; }
    if (i < NROWS) { g_rowbest[i] = 0ULL; g_col_of_row[i] = 0; }
    if (i == 0) g_nrem = 0;
}

// One block per row; float4-coalesced scan; packed-key argmax (ties -> smaller col).
__global__ void k_rowmax(const float* __restrict__ cost) {
    int r = blockIdx.x;
    const float4* row = (const float4*)(cost + (size_t)r * NCOLS);
    u64 best = 0ULL;
    for (int k = threadIdx.x; k < NCOLS / 4; k += blockDim.x) {
        float4 v = row[k];
        int c0 = k * 4;
        u64 k0 = ((u64)fsort(v.x) << 32) | (u32)(NCOLS - 1 - (c0 + 0));
        u64 k1 = ((u64)fsort(v.y) << 32) | (u32)(NCOLS - 1 - (c0 + 1));
        u64 k2 = ((u64)fsort(v.z) << 32) | (u32)(NCOLS - 1 - (c0 + 2));
        u64 k3 = ((u64)fsort(v.w) << 32) | (u32)(NCOLS - 1 - (c0 + 3));
        if (k0 > best) best = k0;
        if (k1 > best) best = k1;
        if (k2 > best) best = k2;
        if (k3 > best) best = k3;
    }
    // wave (64-lane) reduce
    for (int off = 32; off; off >>= 1) {
        u64 o = __shfl_down(best, off);
        if (o > best) best = o;
    }
    __shared__ u64 part[4];  // blockDim = 256 -> 4 waves
    int wave = threadIdx.x >> 6;
    if ((threadIdx.x & 63) == 0) part[wave] = best;
    __syncthreads();
    if (threadIdx.x == 0) {
        u64 b = part[0];
        for (int w = 1; w < 4; w++) if (part[w] > b) b = part[w];
        g_rowbest[r] = b;
    }
}

// grid (NCOLS/256, NROWS/256), block 256: col-major maxima (ties -> smaller row).
__global__ void k_colmax(const float* __restrict__ cost) {
    int c = blockIdx.x * 256 + threadIdx.x;
    int r0 = blockIdx.y * 256;
    u64 best = 0ULL;
    for (int r = r0; r < r0 + 256; ++r) {
        float x = cost[(size_t)r * NCOLS + c];
        u64 k = ((u64)fsort(x) << 32) | (u32)(NROWS - 1 - r);
        if (k > best) best = k;
    }
    atomicMax(&g_colbest[c], best);
}

// 1 block, 1024 threads: commit all round-1 mutual-best pairs, list the rest.
__global__ void k_commit1() {
    int r = threadIdx.x;
    u64 key = g_rowbest[r];
    int c = NCOLS - 1 - (int)(key & 0xFFFFFFFFu);
    u64 mykey_at_c = (key & 0xFFFFFFFF00000000ULL) | (u32)(NROWS - 1 - r);
    if (g_colbest[c] == mykey_at_c) {
        g_col_used[c] = 1;
        g_col_of_row[r] = c;
    } else {
        int p = atomicAdd(&g_nrem, 1);
        g_remaining[p] = r;
    }
}

// 1 block, 1024 threads: finish remaining rows with mutual-best rounds.
__global__ void k_finish(const float* __restrict__ cost) {
    __shared__ int s_rem[2][NROWS];
    __shared__ int s_n, s_newn;
    __shared__ u64 s_part[16];
    int tid = threadIdx.x;
    if (tid == 0) s_n = g_nrem;
    __syncthreads();
    int n = s_n;
    for (int i = tid; i < n; i += blockDim.x) s_rem[0][i] = g_remaining[i];
    __syncthreads();
    int cur = 0;

    while (n > 0) {
        // 1) Recompute rows whose cached best column has been taken.
        for (int i = 0; i < n; i++) {
            int r = s_rem[cur][i];
            u64 key = g_rowbest[r];              // same value read by all threads
            int c = NCOLS - 1 - (int)(key & 0xFFFFFFFFu);
            if (g_col_used[c]) {                 // block-uniform branch
                u64 best = 0ULL;
                const float4* row = (const float4*)(cost + (size_t)r * NCOLS);
                for (int k = tid; k < NCOLS / 4; k += blockDim.x) {
                    float4 v = row[k];
                    int c0 = k * 4;
                    if (!g_col_used[c0 + 0]) { u64 kk = ((u64)fsort(v.x) << 32) | (u32)(NCOLS - 1 - (c0 + 0)); if (kk > best) best = kk; }
                    if (!g_col_used[c0 + 1]) { u64 kk = ((u64)fsort(v.y) << 32) | (u32)(NCOLS - 1 - (c0 + 1)); if (kk > best) best = kk; }
                    if (!g_col_used[c0 + 2]) { u64 kk = ((u64)fsort(v.z) << 32) | (u32)(NCOLS - 1 - (c0 + 2)); if (kk > best) best = kk; }
                    if (!g_col_used[c0 + 3]) { u64 kk = ((u64)fsort(v.w) << 32) | (u32)(NCOLS - 1 - (c0 + 3)); if (kk > best) best = kk; }
                }
                for (int off = 32; off; off >>= 1) {
                    u64 o = __shfl_down(best, off);
                    if (o > best) best = o;
                }
                int wave = tid >> 6;
                if ((tid & 63) == 0) s_part[wave] = best;
                __syncthreads();
                if (tid == 0) {
                    u64 b = s_part[0];
                    for (int w = 1; w < 16; w++) if (s_part[w] > b) b = s_part[w];
                    g_rowbest[r] = b;
                }
                __syncthreads();
            }
        }
        __syncthreads();

        // 2) Winner check: row i wins iff no other remaining row beats it in its column.
        bool win = false; int myr = -1, myc = -1;
        if (tid < n) {
            int r = s_rem[cur][tid];
            u64 key = g_rowbest[r];
            int c = NCOLS - 1 - (int)(key & 0xFFFFFFFFu);
            u64 mine = (key & 0xFFFFFFFF00000000ULL) | (u32)(NROWS - 1 - r);
            win = true;
            for (int j = 0; j < n; j++) {
                int rj = s_rem[cur][j];
                if (rj == r) continue;
                float x = cost[(size_t)rj * NCOLS + c];
                u64 kj = ((u64)fsort(x) << 32) | (u32)(NROWS - 1 - rj);
                if (kj > mine) { win = false; break; }
            }
            myr = r; myc = c;
        }
        __syncthreads();
        if (win) {
            g_col_used[myc] = 1;
            g_col_of_row[myr] = myc;
        }
        if (tid == 0) s_newn = 0;
        __syncthreads();
        if (tid < n && !win) {
            int p = atomicAdd(&s_newn, 1);
            s_rem[cur ^ 1][p] = myr;
        }
        __syncthreads();
        n = s_newn;
        cur ^= 1;
        __syncthreads();
    }
}

__global__ void k_out(int* __restrict__ out) {
    int i = blockIdx.x * blockDim.x + threadIdx.x;
    if (i < NROWS) {
        out[i] = i;                     // rows sorted ascending = identity
        out[NROWS + i] = g_col_of_row[i];
    }
}

extern "C" void kernel_launch(void* const* d_in, const int* in_sizes, int n_in,
                              void* d_out, int out_size, void* d_ws, size_t ws_size,
                              hipStream_t stream) {
    const float* cost = (const float*)d_in[0];
    int* out = (int*)d_out;

    k_init<<<NCOLS / 256, 256, 0, stream>>>();
    k_rowmax<<<NROWS, 256, 0, stream>>>(cost);
    k_colmax<<<dim3(NCOLS / 256, NROWS / 256), 256, 0, stream>>>(cost);
    k_commit1<<<1, 1024, 0, stream>>>();
    k_finish<<<1, 1024, 0, stream>>>(cost);
    k_out<<<(2 * NROWS + 255) / 256, 256, 0, stream>>>(out);
}

// Round 2
// 189.576 us; speedup vs baseline: 2.2693x; 2.2693x over previous
//
#include <hip/hip_runtime.h>
#include <stdint.h>

#define NROWS 1024
#define NCOLS 16384
#define NROUNDS 4

typedef unsigned long long u64;
typedef unsigned int u32;

// Persistent device state (re-initialized every kernel_launch call).
__device__ u64 g_rowbest[NROWS];    // key: (sortable_val<<32) | (NCOLS-1-col)
__device__ u64 g_colbest[NCOLS];    // key: (sortable_val<<32) | (NROWS-1-row)
__device__ int g_col_used[NCOLS];
__device__ int g_row_assigned[NROWS];
__device__ int g_col_of_row[NROWS];
__device__ int g_remaining[NROWS];
__device__ int g_nrem;

// Monotone float32 -> uint32 mapping (preserves <):
__device__ __forceinline__ u32 fsort(float x) {
    u32 u = __float_as_uint(x);
    return u ^ ((u32)((int)u >> 31) | 0x80000000u);
}

__global__ void k_init() {
    int i = blockIdx.x * blockDim.x + threadIdx.x;
    if (i < NCOLS) { g_colbest[i] = 0ULL; g_col_used[i] = 0; }
    if (i < NROWS) { g_rowbest[i] = 0ULL; g_col_of_row[i] = 0; g_row_assigned[i] = 0; }
    if (i == 0) g_nrem = 0;
}

// One block per row; float4-coalesced scan; packed-key argmax (ties -> smaller col).
__global__ void k_rowmax(const float* __restrict__ cost) {
    int r = blockIdx.x;
    const float4* row = (const float4*)(cost + (size_t)r * NCOLS);
    u64 best = 0ULL;
    for (int k = threadIdx.x; k < NCOLS / 4; k += blockDim.x) {
        float4 v = row[k];
        int c0 = k * 4;
        u64 k0 = ((u64)fsort(v.x) << 32) | (u32)(NCOLS - 1 - (c0 + 0));
        u64 k1 = ((u64)fsort(v.y) << 32) | (u32)(NCOLS - 1 - (c0 + 1));
        u64 k2 = ((u64)fsort(v.z) << 32) | (u32)(NCOLS - 1 - (c0 + 2));
        u64 k3 = ((u64)fsort(v.w) << 32) | (u32)(NCOLS - 1 - (c0 + 3));
        if (k0 > best) best = k0;
        if (k1 > best) best = k1;
        if (k2 > best) best = k2;
        if (k3 > best) best = k3;
    }
    for (int off = 32; off; off >>= 1) {
        u64 o = __shfl_down(best, off);
        if (o > best) best = o;
    }
    __shared__ u64 part[4];  // blockDim = 256 -> 4 waves
    int wave = threadIdx.x >> 6;
    if ((threadIdx.x & 63) == 0) part[wave] = best;
    __syncthreads();
    if (threadIdx.x == 0) {
        u64 b = part[0];
        for (int w = 1; w < 4; w++) if (part[w] > b) b = part[w];
        g_rowbest[r] = b;
    }
}

// grid (NCOLS/256, NROWS/256), block 256: col-major maxima (ties -> smaller row).
__global__ void k_colmax(const float* __restrict__ cost) {
    int c = blockIdx.x * 256 + threadIdx.x;
    int r0 = blockIdx.y * 256;
    u64 best = 0ULL;
    for (int r = r0; r < r0 + 256; ++r) {
        float x = cost[(size_t)r * NCOLS + c];
        u64 k = ((u64)fsort(x) << 32) | (u32)(NROWS - 1 - r);
        if (k > best) best = k;
    }
    atomicMax(&g_colbest[c], best);
}

// 1 block, 1024 threads: commit all round-1 mutual-best pairs, list the rest.
__global__ void k_commit1() {
    int r = threadIdx.x;
    u64 key = g_rowbest[r];
    int c = NCOLS - 1 - (int)(key & 0xFFFFFFFFu);
    u64 mykey_at_c = (key & 0xFFFFFFFF00000000ULL) | (u32)(NROWS - 1 - r);
    if (g_colbest[c] == mykey_at_c) {
        g_col_used[c] = 1;
        g_col_of_row[r] = c;
        g_row_assigned[r] = 1;
    } else {
        int p = atomicAdd(&g_nrem, 1);
        g_remaining[p] = r;
    }
}

// One block per row: rescan rows whose cached best column has been taken.
// Blocks for assigned rows / fresh rows exit immediately -> runs in parallel
// only for the ~stale rows.
__global__ void k_recompute(const float* __restrict__ cost) {
    int r = blockIdx.x;
    if (g_row_assigned[r]) return;
    u64 key = g_rowbest[r];
    int cbest = NCOLS - 1 - (int)(key & 0xFFFFFFFFu);
    if (!g_col_used[cbest]) return;   // cache still valid

    u64 best = 0ULL;
    const float4* row = (const float4*)(cost + (size_t)r * NCOLS);
    const int4* used = (const int4*)g_col_used;
    for (int k = threadIdx.x; k < NCOLS / 4; k += blockDim.x) {
        float4 v = row[k];
        int4 u = used[k];
        int c0 = k * 4;
        if (!u.x) { u64 kk = ((u64)fsort(v.x) << 32) | (u32)(NCOLS - 1 - (c0 + 0)); if (kk > best) best = kk; }
        if (!u.y) { u64 kk = ((u64)fsort(v.y) << 32) | (u32)(NCOLS - 1 - (c0 + 1)); if (kk > best) best = kk; }
        if (!u.z) { u64 kk = ((u64)fsort(v.z) << 32) | (u32)(NCOLS - 1 - (c0 + 2)); if (kk > best) best = kk; }
        if (!u.w) { u64 kk = ((u64)fsort(v.w) << 32) | (u32)(NCOLS - 1 - (c0 + 3)); if (kk > best) best = kk; }
    }
    for (int off = 32; off; off >>= 1) {
        u64 o = __shfl_down(best, off);
        if (o > best) best = o;
    }
    __shared__ u64 part[4];
    int wave = threadIdx.x >> 6;
    if ((threadIdx.x & 63) == 0) part[wave] = best;
    __syncthreads();
    if (threadIdx.x == 0) {
        u64 b = part[0];
        for (int w = 1; w < 4; w++) if (part[w] > b) b = part[w];
        g_rowbest[r] = b;
    }
}

// 1 block, 1024 threads: mutual-best winner check among unassigned rows,
// commit winners, rebuild remaining list.
__global__ void k_round(const float* __restrict__ cost) {
    __shared__ int s_list[NROWS];
    __shared__ int s_n;
    int tid = threadIdx.x;
    if (tid == 0) s_n = 0;
    __syncthreads();
    int r = tid;
    bool unassigned = !g_row_assigned[r];
    if (unassigned) { int p = atomicAdd(&s_n, 1); s_list[p] = r; }
    __syncthreads();
    int n = s_n;
    if (n == 0) { if (tid == 0) g_nrem = 0; return; }

    int c = -1;
    u64 mine = 0;
    bool win = false;
    if (unassigned) {
        u64 key = g_rowbest[r];
        c = NCOLS - 1 - (int)(key & 0xFFFFFFFFu);
        mine = (key & 0xFFFFFFFF00000000ULL) | (u32)(NROWS - 1 - r);
        win = true;
        for (int j = 0; j < n; j++) {
            int rj = s_list[j];
            if (rj == r) continue;
            float x = cost[(size_t)rj * NCOLS + c];
            u64 kj = ((u64)fsort(x) << 32) | (u32)(NROWS - 1 - rj);
            if (kj > mine) { win = false; break; }
        }
    }
    if (win) {
        g_col_used[c] = 1;
        g_col_of_row[r] = c;
        g_row_assigned[r] = 1;
    }
    __syncthreads();
    if (tid == 0) s_n = 0;
    __syncthreads();
    if (unassigned && !win) {
        int p = atomicAdd(&s_n, 1);
        g_remaining[p] = r;
    }
    __syncthreads();
    if (tid == 0) g_nrem = s_n;
}

// Correctness fallback: persistent single-block loop (normally sees n==0 and
// exits immediately; only runs the slow path on pathological inputs).
__global__ void k_finish(const float* __restrict__ cost) {
    __shared__ int s_rem[2][NROWS];
    __shared__ int s_n, s_newn;
    __shared__ u64 s_part[16];
    int tid = threadIdx.x;
    if (tid == 0) s_n = g_nrem;
    __syncthreads();
    int n = s_n;
    if (n == 0) return;
    for (int i = tid; i < n; i += blockDim.x) s_rem[0][i] = g_remaining[i];
    __syncthreads();
    int cur = 0;

    while (n > 0) {
        for (int i = 0; i < n; i++) {
            int r = s_rem[cur][i];
            u64 key = g_rowbest[r];
            int c = NCOLS - 1 - (int)(key & 0xFFFFFFFFu);
            if (g_col_used[c]) {
                u64 best = 0ULL;
                const float4* row = (const float4*)(cost + (size_t)r * NCOLS);
                for (int k = tid; k < NCOLS / 4; k += blockDim.x) {
                    float4 v = row[k];
                    int c0 = k * 4;
                    if (!g_col_used[c0 + 0]) { u64 kk = ((u64)fsort(v.x) << 32) | (u32)(NCOLS - 1 - (c0 + 0)); if (kk > best) best = kk; }
                    if (!g_col_used[c0 + 1]) { u64 kk = ((u64)fsort(v.y) << 32) | (u32)(NCOLS - 1 - (c0 + 1)); if (kk > best) best = kk; }
                    if (!g_col_used[c0 + 2]) { u64 kk = ((u64)fsort(v.z) << 32) | (u32)(NCOLS - 1 - (c0 + 2)); if (kk > best) best = kk; }
                    if (!g_col_used[c0 + 3]) { u64 kk = ((u64)fsort(v.w) << 32) | (u32)(NCOLS - 1 - (c0 + 3)); if (kk > best) best = kk; }
                }
                for (int off = 32; off; off >>= 1) {
                    u64 o = __shfl_down(best, off);
                    if (o > best) best = o;
                }
                int wave = tid >> 6;
                if ((tid & 63) == 0) s_part[wave] = best;
                __syncthreads();
                if (tid == 0) {
                    u64 b = s_part[0];
                    for (int w = 1; w < 16; w++) if (s_part[w] > b) b = s_part[w];
                    g_rowbest[r] = b;
                }
                __syncthreads();
            }
        }
        __syncthreads();

        bool win = false; int myr = -1, myc = -1;
        if (tid < n) {
            int r = s_rem[cur][tid];
            u64 key = g_rowbest[r];
            int c = NCOLS - 1 - (int)(key & 0xFFFFFFFFu);
            u64 mine = (key & 0xFFFFFFFF00000000ULL) | (u32)(NROWS - 1 - r);
            win = true;
            for (int j = 0; j < n; j++) {
                int rj = s_rem[cur][j];
                if (rj == r) continue;
                float x = cost[(size_t)rj * NCOLS + c];
                u64 kj = ((u64)fsort(x) << 32) | (u32)(NROWS - 1 - rj);
                if (kj > mine) { win = false; break; }
            }
            myr = r; myc = c;
        }
        __syncthreads();
        if (win) {
            g_col_used[myc] = 1;
            g_col_of_row[myr] = myc;
            g_row_assigned[myr] = 1;
        }
        if (tid == 0) s_newn = 0;
        __syncthreads();
        if (tid < n && !win) {
            int p = atomicAdd(&s_newn, 1);
            s_rem[cur ^ 1][p] = myr;
        }
        __syncthreads();
        n = s_newn;
        cur ^= 1;
        __syncthreads();
    }
}

__global__ void k_out(int* __restrict__ out) {
    int i = blockIdx.x * blockDim.x + threadIdx.x;
    if (i < NROWS) {
        out[i] = i;                     // rows sorted ascending = identity
        out[NROWS + i] = g_col_of_row[i];
    }
}

extern "C" void kernel_launch(void* const* d_in, const int* in_sizes, int n_in,
                              void* d_out, int out_size, void* d_ws, size_t ws_size,
                              hipStream_t stream) {
    const float* cost = (const float*)d_in[0];
    int* out = (int*)d_out;

    k_init<<<NCOLS / 256, 256, 0, stream>>>();
    k_rowmax<<<NROWS, 256, 0, stream>>>(cost);
    k_colmax<<<dim3(NCOLS / 256, NROWS / 256), 256, 0, stream>>>(cost);
    k_commit1<<<1, 1024, 0, stream>>>();
    for (int round = 0; round < NROUNDS; ++round) {
        k_recompute<<<NROWS, 256, 0, stream>>>(cost);
        k_round<<<1, 1024, 0, stream>>>(cost);
    }
    k_finish<<<1, 1024, 0, stream>>>(cost);
    k_out<<<(2 * NROWS + 255) / 256, 256, 0, stream>>>(out);
}

// Round 3
// 156.447 us; speedup vs baseline: 2.7498x; 1.2118x over previous
//
#include <hip/hip_runtime.h>
#include <stdint.h>

#define NROWS 1024
#define NCOLS 16384
#define NROUNDS 3

typedef unsigned long long u64;
typedef unsigned int u32;

// Persistent device state (re-initialized every kernel_launch call).
__device__ u64 g_rowbest[NROWS];    // key: (sortable_val<<32) | (NCOLS-1-col)
__device__ u64 g_colbest[NCOLS];    // key: (sortable_val<<32) | (NROWS-1-row)
__device__ int g_col_used[NCOLS];
__device__ int g_row_assigned[NROWS];
__device__ int g_col_of_row[NROWS];
__device__ int g_remaining[NROWS];
__device__ int g_nrem;

// Monotone float32 -> uint32 mapping (preserves <):
__device__ __forceinline__ u32 fsort(float x) {
    u32 u = __float_as_uint(x);
    return u ^ ((u32)((int)u >> 31) | 0x80000000u);
}

__global__ void k_init(int* __restrict__ out) {
    int i = blockIdx.x * blockDim.x + threadIdx.x;
    if (i < NCOLS) { g_colbest[i] = 0ULL; g_col_used[i] = 0; }
    if (i < NROWS) {
        g_rowbest[i] = 0ULL; g_col_of_row[i] = 0; g_row_assigned[i] = 0;
        out[i] = i;          // rows sorted ascending = identity
    }
    if (i == 0) g_nrem = 0;
}

// One block per row; float4-coalesced scan; packed-key argmax (ties -> smaller col).
__global__ void k_rowmax(const float* __restrict__ cost) {
    int r = blockIdx.x;
    const float4* row = (const float4*)(cost + (size_t)r * NCOLS);
    u64 best = 0ULL;
    for (int k = threadIdx.x; k < NCOLS / 4; k += blockDim.x) {
        float4 v = row[k];
        int c0 = k * 4;
        u64 k0 = ((u64)fsort(v.x) << 32) | (u32)(NCOLS - 1 - (c0 + 0));
        u64 k1 = ((u64)fsort(v.y) << 32) | (u32)(NCOLS - 1 - (c0 + 1));
        u64 k2 = ((u64)fsort(v.z) << 32) | (u32)(NCOLS - 1 - (c0 + 2));
        u64 k3 = ((u64)fsort(v.w) << 32) | (u32)(NCOLS - 1 - (c0 + 3));
        if (k0 > best) best = k0;
        if (k1 > best) best = k1;
        if (k2 > best) best = k2;
        if (k3 > best) best = k3;
    }
    for (int off = 32; off; off >>= 1) {
        u64 o = __shfl_down(best, off);
        if (o > best) best = o;
    }
    __shared__ u64 part[4];  // blockDim = 256 -> 4 waves
    int wave = threadIdx.x >> 6;
    if ((threadIdx.x & 63) == 0) part[wave] = best;
    __syncthreads();
    if (threadIdx.x == 0) {
        u64 b = part[0];
        for (int w = 1; w < 4; w++) if (part[w] > b) b = part[w];
        g_rowbest[r] = b;
    }
}

// grid (NCOLS/1024, NROWS/64), block 256: each thread covers 4 cols (float4),
// 64 rows. Col maxima with ties -> smaller row. 4 atomicMax per thread.
__global__ void k_colmax(const float* __restrict__ cost) {
    int c0 = blockIdx.x * 1024 + threadIdx.x * 4;
    int r0 = blockIdx.y * 64;
    u64 b0 = 0, b1 = 0, b2 = 0, b3 = 0;
    for (int r = r0; r < r0 + 64; ++r) {
        float4 v = *(const float4*)(cost + (size_t)r * NCOLS + c0);
        u32 rk = (u32)(NROWS - 1 - r);
        u64 k0 = ((u64)fsort(v.x) << 32) | rk;
        u64 k1 = ((u64)fsort(v.y) << 32) | rk;
        u64 k2 = ((u64)fsort(v.z) << 32) | rk;
        u64 k3 = ((u64)fsort(v.w) << 32) | rk;
        if (k0 > b0) b0 = k0;
        if (k1 > b1) b1 = k1;
        if (k2 > b2) b2 = k2;
        if (k3 > b3) b3 = k3;
    }
    atomicMax(&g_colbest[c0 + 0], b0);
    atomicMax(&g_colbest[c0 + 1], b1);
    atomicMax(&g_colbest[c0 + 2], b2);
    atomicMax(&g_colbest[c0 + 3], b3);
}

// 1 block, 1024 threads: commit all round-1 mutual-best pairs, list the rest.
__global__ void k_commit1(int* __restrict__ out) {
    int r = threadIdx.x;
    u64 key = g_rowbest[r];
    int c = NCOLS - 1 - (int)(key & 0xFFFFFFFFu);
    u64 mykey_at_c = (key & 0xFFFFFFFF00000000ULL) | (u32)(NROWS - 1 - r);
    if (g_colbest[c] == mykey_at_c) {
        g_col_used[c] = 1;
        g_col_of_row[r] = c;
        g_row_assigned[r] = 1;
        out[NROWS + r] = c;
    } else {
        int p = atomicAdd(&g_nrem, 1);
        g_remaining[p] = r;
    }
}

// One block per row: rescan rows whose cached best column has been taken.
// Blocks for assigned/fresh rows exit immediately.
__global__ void k_recompute(const float* __restrict__ cost) {
    int r = blockIdx.x;
    if (g_row_assigned[r]) return;
    u64 key = g_rowbest[r];
    int cbest = NCOLS - 1 - (int)(key & 0xFFFFFFFFu);
    if (!g_col_used[cbest]) return;   // cache still valid

    u64 best = 0ULL;
    const float4* row = (const float4*)(cost + (size_t)r * NCOLS);
    const int4* used = (const int4*)g_col_used;
    for (int k = threadIdx.x; k < NCOLS / 4; k += blockDim.x) {
        float4 v = row[k];
        int4 u = used[k];
        int c0 = k * 4;
        if (!u.x) { u64 kk = ((u64)fsort(v.x) << 32) | (u32)(NCOLS - 1 - (c0 + 0)); if (kk > best) best = kk; }
        if (!u.y) { u64 kk = ((u64)fsort(v.y) << 32) | (u32)(NCOLS - 1 - (c0 + 1)); if (kk > best) best = kk; }
        if (!u.z) { u64 kk = ((u64)fsort(v.z) << 32) | (u32)(NCOLS - 1 - (c0 + 2)); if (kk > best) best = kk; }
        if (!u.w) { u64 kk = ((u64)fsort(v.w) << 32) | (u32)(NCOLS - 1 - (c0 + 3)); if (kk > best) best = kk; }
    }
    for (int off = 32; off; off >>= 1) {
        u64 o = __shfl_down(best, off);
        if (o > best) best = o;
    }
    __shared__ u64 part[4];
    int wave = threadIdx.x >> 6;
    if ((threadIdx.x & 63) == 0) part[wave] = best;
    __syncthreads();
    if (threadIdx.x == 0) {
        u64 b = part[0];
        for (int w = 1; w < 4; w++) if (part[w] > b) b = part[w];
        g_rowbest[r] = b;
    }
}

// 1 block, 1024 threads: parallel mutual-best winner check among unassigned
// rows (n^2 pair checks spread over all threads), commit winners.
__global__ void k_round(const float* __restrict__ cost, int* __restrict__ out) {
    __shared__ int s_list[NROWS];
    __shared__ int s_cand[NROWS];
    __shared__ u64 s_mine[NROWS];
    __shared__ u64 s_max[NROWS];
    __shared__ int s_n;
    int tid = threadIdx.x;
    if (tid == 0) s_n = 0;
    __syncthreads();
    int r = tid;
    bool unassigned = !g_row_assigned[r];
    int mypos = -1;
    if (unassigned) { mypos = atomicAdd(&s_n, 1); s_list[mypos] = r; }
    __syncthreads();
    int n = s_n;
    if (n == 0) { if (tid == 0) g_nrem = 0; return; }

    if (unassigned) {
        u64 key = g_rowbest[r];
        int c = NCOLS - 1 - (int)(key & 0xFFFFFFFFu);
        s_cand[mypos] = c;
        s_mine[mypos] = (key & 0xFFFFFFFF00000000ULL) | (u32)(NROWS - 1 - r);
        s_max[mypos] = 0ULL;
    }
    __syncthreads();

    // Pair checks: for each listed row i, max over listed rows j of key_j at col c_i.
    for (int idx = tid; idx < n * n; idx += blockDim.x) {
        int i = idx / n;
        int j = idx - i * n;
        int c = s_cand[i];
        int rj = s_list[j];
        float x = cost[(size_t)rj * NCOLS + c];
        u64 kj = ((u64)fsort(x) << 32) | (u32)(NROWS - 1 - rj);
        atomicMax(&s_max[i], kj);
    }
    __syncthreads();

    bool win = unassigned && (s_max[mypos] == s_mine[mypos]);  // keys unique
    if (win) {
        int c = s_cand[mypos];
        g_col_used[c] = 1;
        g_col_of_row[r] = c;
        g_row_assigned[r] = 1;
        out[NROWS + r] = c;
    }
    __syncthreads();
    if (tid == 0) s_n = 0;
    __syncthreads();
    if (unassigned && !win) {
        int p = atomicAdd(&s_n, 1);
        g_remaining[p] = r;
    }
    __syncthreads();
    if (tid == 0) g_nrem = s_n;
}

// Correctness fallback: persistent single-block loop (normally sees n==0 and
// exits immediately; only runs the slow path on pathological inputs).
__global__ void k_finish(const float* __restrict__ cost, int* __restrict__ out) {
    __shared__ int s_rem[2][NROWS];
    __shared__ int s_n, s_newn;
    __shared__ u64 s_part[16];
    int tid = threadIdx.x;
    if (tid == 0) s_n = g_nrem;
    __syncthreads();
    int n = s_n;
    if (n == 0) return;
    for (int i = tid; i < n; i += blockDim.x) s_rem[0][i] = g_remaining[i];
    __syncthreads();
    int cur = 0;

    while (n > 0) {
        for (int i = 0; i < n; i++) {
            int r = s_rem[cur][i];
            u64 key = g_rowbest[r];
            int c = NCOLS - 1 - (int)(key & 0xFFFFFFFFu);
            if (g_col_used[c]) {
                u64 best = 0ULL;
                const float4* row = (const float4*)(cost + (size_t)r * NCOLS);
                for (int k = tid; k < NCOLS / 4; k += blockDim.x) {
                    float4 v = row[k];
                    int c0 = k * 4;
                    if (!g_col_used[c0 + 0]) { u64 kk = ((u64)fsort(v.x) << 32) | (u32)(NCOLS - 1 - (c0 + 0)); if (kk > best) best = kk; }
                    if (!g_col_used[c0 + 1]) { u64 kk = ((u64)fsort(v.y) << 32) | (u32)(NCOLS - 1 - (c0 + 1)); if (kk > best) best = kk; }
                    if (!g_col_used[c0 + 2]) { u64 kk = ((u64)fsort(v.z) << 32) | (u32)(NCOLS - 1 - (c0 + 2)); if (kk > best) best = kk; }
                    if (!g_col_used[c0 + 3]) { u64 kk = ((u64)fsort(v.w) << 32) | (u32)(NCOLS - 1 - (c0 + 3)); if (kk > best) best = kk; }
                }
                for (int off = 32; off; off >>= 1) {
                    u64 o = __shfl_down(best, off);
                    if (o > best) best = o;
                }
                int wave = tid >> 6;
                if ((tid & 63) == 0) s_part[wave] = best;
                __syncthreads();
                if (tid == 0) {
                    u64 b = s_part[0];
                    for (int w = 1; w < 16; w++) if (s_part[w] > b) b = s_part[w];
                    g_rowbest[r] = b;
                }
                __syncthreads();
            }
        }
        __syncthreads();

        bool win = false; int myr = -1, myc = -1;
        if (tid < n) {
            int r = s_rem[cur][tid];
            u64 key = g_rowbest[r];
            int c = NCOLS - 1 - (int)(key & 0xFFFFFFFFu);
            u64 mine = (key & 0xFFFFFFFF00000000ULL) | (u32)(NROWS - 1 - r);
            win = true;
            for (int j = 0; j < n; j++) {
                int rj = s_rem[cur][j];
                if (rj == r) continue;
                float x = cost[(size_t)rj * NCOLS + c];
                u64 kj = ((u64)fsort(x) << 32) | (u32)(NROWS - 1 - rj);
                if (kj > mine) { win = false; break; }
            }
            myr = r; myc = c;
        }
        __syncthreads();
        if (win) {
            g_col_used[myc] = 1;
            g_col_of_row[myr] = myc;
            g_row_assigned[myr] = 1;
            out[NROWS + myr] = myc;
        }
        if (tid == 0) s_newn = 0;
        __syncthreads();
        if (tid < n && !win) {
            int p = atomicAdd(&s_newn, 1);
            s_rem[cur ^ 1][p] = myr;
        }
        __syncthreads();
        n = s_newn;
        cur ^= 1;
        __syncthreads();
    }
}

extern "C" void kernel_launch(void* const* d_in, const int* in_sizes, int n_in,
                              void* d_out, int out_size, void* d_ws, size_t ws_size,
                              hipStream_t stream) {
    const float* cost = (const float*)d_in[0];
    int* out = (int*)d_out;

    k_init<<<NCOLS / 256, 256, 0, stream>>>(out);
    k_rowmax<<<NROWS, 256, 0, stream>>>(cost);
    k_colmax<<<dim3(NCOLS / 1024, NROWS / 64), 256, 0, stream>>>(cost);
    k_commit1<<<1, 1024, 0, stream>>>(out);
    for (int round = 0; round < NROUNDS; ++round) {
        k_recompute<<<NROWS, 256, 0, stream>>>(cost);
        k_round<<<1, 1024, 0, stream>>>(cost, out);
    }
    k_finish<<<1, 1024, 0, stream>>>(cost, out);
}